// Round 1
// 533.374 us; speedup vs baseline: 1.0079x; 1.0079x over previous
//
#include <hip/hip_runtime.h>

typedef unsigned short u16;
typedef __attribute__((ext_vector_type(8))) short short8;
typedef __attribute__((ext_vector_type(4))) float floatx4;

#define MFMA16(a, b, c) __builtin_amdgcn_mfma_f32_16x16x32_bf16(a, b, c, 0, 0, 0)

__device__ __forceinline__ float bf2f(u16 u) {
  return __uint_as_float(((unsigned int)u) << 16);
}
__device__ __forceinline__ u16 f2bf(float f) {
  unsigned int u = __float_as_uint(f);
  unsigned int r = (u + 0x7fffu + ((u >> 16) & 1u)) >> 16;
  return (u16)r;
}

// ---------------------------------------------------------------- LayerNorm: fp32 x -> bf16 h
__global__ __launch_bounds__(256) void ln_kernel(
    const float* __restrict__ x, const float* __restrict__ w, const float* __restrict__ bb,
    u16* __restrict__ hb)
{
  int wid = threadIdx.x >> 6, lane = threadIdx.x & 63;
  int row = blockIdx.x * 4 + wid;
  const float* xr = x + row * 1024 + lane * 16;
  float xs[16];
#pragma unroll
  for (int i = 0; i < 4; i++) {
    float4 v = *(const float4*)(xr + i * 4);
    xs[i * 4 + 0] = v.x; xs[i * 4 + 1] = v.y; xs[i * 4 + 2] = v.z; xs[i * 4 + 3] = v.w;
  }
  float s = 0.f, ss = 0.f;
#pragma unroll
  for (int i = 0; i < 16; i++) { s += xs[i]; ss += xs[i] * xs[i]; }
#pragma unroll
  for (int m = 1; m < 64; m <<= 1) { s += __shfl_xor(s, m, 64); ss += __shfl_xor(ss, m, 64); }
  float mu = s * (1.0f / 1024.0f);
  float var = ss * (1.0f / 1024.0f) - mu * mu;
  float rstd = rsqrtf(var + 1e-5f);
  const float* wr = w + lane * 16;
  const float* br = bb + lane * 16;
  short8 o0, o1;
#pragma unroll
  for (int i = 0; i < 8; i++) {
    o0[i] = (short)f2bf((xs[i] - mu) * rstd * wr[i] + br[i]);
    o1[i] = (short)f2bf((xs[8 + i] - mu) * rstd * wr[8 + i] + br[8 + i]);
  }
  u16* hr = hb + row * 1024 + lane * 16;
  *(short8*)hr = o0;
  *(short8*)(hr + 8) = o1;
}

// ---------------------------------------------------------------- convert wq|wk|wv|wo fp32 -> bf16
__global__ __launch_bounds__(256) void convw_kernel(
    const float* __restrict__ wq, const float* __restrict__ wk,
    const float* __restrict__ wv, const float* __restrict__ wo,
    u16* __restrict__ wb)
{
  int idx = (blockIdx.x * 256 + threadIdx.x) * 8;  // [0, 4M)
  int seg = idx >> 20, off = idx & 1048575;
  const float* s = (seg == 0) ? wq : (seg == 1) ? wk : (seg == 2) ? wv : wo;
  float4 f0 = *(const float4*)(s + off);
  float4 f1 = *(const float4*)(s + off + 4);
  short8 o;
  o[0] = (short)f2bf(f0.x); o[1] = (short)f2bf(f0.y);
  o[2] = (short)f2bf(f0.z); o[3] = (short)f2bf(f0.w);
  o[4] = (short)f2bf(f1.x); o[5] = (short)f2bf(f1.y);
  o[6] = (short)f2bf(f1.z); o[7] = (short)f2bf(f1.w);
  *(short8*)&wb[idx] = o;
}

// ---------------------------------------------------------------- relative bucket helper
__device__ __forceinline__ int rel_bucket(int t, int s) {
  int rel = s - t;
  int bucket = (rel > 0) ? 160 : 0;
  int n = (rel < 0) ? -rel : rel;
  if (n < 80) return bucket + n;
  float a = logf((float)n / 80.0f);          // f32, mirrors np order of ops
  float c = a / (float)2.302585092994046;    // np.log(10.0)
  float v = c * 80.0f;
  int large = 80 + (int)v;                   // trunc toward zero (v >= 0)
  if (large > 159) large = 159;
  return bucket + large;
}

// ---------------------------------------------------------------- compact bias table: tbl[h][2048], rel = idx-1023
__global__ __launch_bounds__(256) void bias_table_kernel(
    const float* __restrict__ rel_emb, float* __restrict__ tbl)
{
  int idx = blockIdx.x * 256 + threadIdx.x;  // [0, 32768)
  int h = idx & 15, ri = idx >> 4;           // ri in [0,2048)
  float v = 0.f;
  if (ri < 2047) {
    int rel = ri - 1023;
    v = rel_emb[rel_bucket(0, rel) * 16 + h];
  }
  tbl[h * 2048 + ri] = v;
}

// ---------------------------------------------------------------- fused QKV GEMM (bf16 operands)
// q scaled by 0.125 -> [b,h,t,hd]; k -> [b,h,t,hd]; v -> [b,h,t,hd] (transposed later). All bf16.
__global__ __launch_bounds__(256) void qkv_kernel(
    const u16* __restrict__ hb, const u16* __restrict__ wb,
    const float* __restrict__ bq, const float* __restrict__ bk, const float* __restrict__ bv,
    u16* __restrict__ qs, u16* __restrict__ kko, u16* __restrict__ vn)
{
  __shared__ u16 As[128 * 32];
  __shared__ u16 Bs[128 * 32];
  int tid = threadIdx.x;
  int wid = tid >> 6, lane = tid & 63;
  int wm = wid >> 1, wn = wid & 1;
  int l15 = lane & 15, quad = lane >> 4;
  int m0 = blockIdx.y * 128;
  int n0g = blockIdx.x * 128;
  int sec = n0g >> 10;
  int n0 = n0g & 1023;
  const u16* W = wb + sec * 1048576;
  const float* bias = (sec == 0) ? bq : ((sec == 1) ? bk : bv);

  floatx4 zero4 = {0.f, 0.f, 0.f, 0.f};
  floatx4 acc[4][4];
#pragma unroll
  for (int i = 0; i < 4; i++)
#pragma unroll
    for (int j = 0; j < 4; j++) acc[i][j] = zero4;

  int lr = tid >> 2;
  int lc = (tid & 3) * 8;

  for (int kt = 0; kt < 1024; kt += 32) {
    *(short8*)&As[lr * 32 + lc]        = *(const short8*)&hb[(m0 + lr) * 1024 + kt + lc];
    *(short8*)&As[(lr + 64) * 32 + lc] = *(const short8*)&hb[(m0 + lr + 64) * 1024 + kt + lc];
    *(short8*)&Bs[lr * 32 + lc]        = *(const short8*)&W[(n0 + lr) * 1024 + kt + lc];
    *(short8*)&Bs[(lr + 64) * 32 + lc] = *(const short8*)&W[(n0 + lr + 64) * 1024 + kt + lc];
    __syncthreads();
    short8 af[4], bf[4];
#pragma unroll
    for (int mi = 0; mi < 4; mi++)
      af[mi] = *(const short8*)&As[(wm * 64 + mi * 16 + l15) * 32 + quad * 8];
#pragma unroll
    for (int ni = 0; ni < 4; ni++)
      bf[ni] = *(const short8*)&Bs[(wn * 64 + ni * 16 + l15) * 32 + quad * 8];
#pragma unroll
    for (int mi = 0; mi < 4; mi++)
#pragma unroll
      for (int ni = 0; ni < 4; ni++)
        acc[mi][ni] = MFMA16(af[mi], bf[ni], acc[mi][ni]);
    __syncthreads();
  }

  int bidx = m0 >> 10;  // batch (128 divides 1024, so uniform per block)
#pragma unroll
  for (int mi = 0; mi < 4; mi++) {
#pragma unroll
    for (int ni = 0; ni < 4; ni++) {
#pragma unroll
      for (int r = 0; r < 4; r++) {
        int row = m0 + wm * 64 + mi * 16 + quad * 4 + r;
        int t = row & 1023;
        int c = n0 + wn * 64 + ni * 16 + l15;   // 0..1023 within section
        float val = acc[mi][ni][r] + bias[c];
        int hh = c >> 6, hp = c & 63;
        if (sec == 0) {
          val *= 0.125f;
          qs[((bidx * 16 + hh) * 1024 + t) * 64 + hp] = f2bf(val);
        } else if (sec == 1) {
          kko[((bidx * 16 + hh) * 1024 + t) * 64 + hp] = f2bf(val);
        } else {
          vn[((bidx * 16 + hh) * 1024 + t) * 64 + hp] = f2bf(val);  // coalesced; transpose in vtrans
        }
      }
    }
  }
}

// ---------------------------------------------------------------- V transpose: [bh][t][hd] -> [bh][hd][t]
__global__ __launch_bounds__(256) void vtrans_kernel(
    const u16* __restrict__ vn, u16* __restrict__ vt)
{
  __shared__ u16 Ts[64 * 72];
  int bh = blockIdx.x >> 4;
  int t0 = (blockIdx.x & 15) * 64;
  int tid = threadIdx.x;
  int row = tid >> 2;            // 0..63
  int c16 = (tid & 3) * 16;      // 0,16,32,48
  const u16* src = vn + bh * 65536 + (t0 + row) * 64 + c16;
  *(short8*)&Ts[row * 72 + c16]     = *(const short8*)&src[0];
  *(short8*)&Ts[row * 72 + c16 + 8] = *(const short8*)&src[8];
  __syncthreads();
  short8 o0, o1;
#pragma unroll
  for (int j = 0; j < 8; j++) {
    o0[j] = (short)Ts[(c16 + j) * 72 + row];
    o1[j] = (short)Ts[(c16 + 8 + j) * 72 + row];
  }
  u16* dst = vt + bh * 65536 + row * 1024 + t0 + c16;
  *(short8*)&dst[0] = o0;
  *(short8*)&dst[8] = o1;
}

// ---------------------------------------------------------------- flash attention (gate fused, swapped-QK softmax)
// grid (64 bh, 16 qtiles); 4 waves/block, each wave owns 16 q-rows (q = l15-local), s-steps of 32.
__global__ __launch_bounds__(256) void attn_kernel(
    const u16* __restrict__ qs, const u16* __restrict__ kko, const u16* __restrict__ vt,
    const float* __restrict__ gw, const float* __restrict__ gb, const float* __restrict__ ga,
    const float* __restrict__ tbl, u16* __restrict__ ao)
{
  __shared__ __align__(16) u16 Pb[4][2 * 768];  // per-wave double-buffered: 16 rows x 48 stride
  int wid = threadIdx.x >> 6, lane = threadIdx.x & 63;
  int l15 = lane & 15, quad = lane >> 4;
  int bh = blockIdx.x;
  int b = bh >> 4, h = bh & 15;
  int q0 = blockIdx.y * 64 + wid * 16;
  const u16* Q = qs + bh * 65536;
  const u16* K = kko + bh * 65536;
  const u16* V = vt + bh * 65536;       // [hd][t]
  u16* pbase = &Pb[wid][0];

  // ---- gate for q-row q0 + l15; quads split the 64-dim dot, xor-reduce ----
  const u16* qrow = Q + (q0 + l15) * 64;
  float e[8];
#pragma unroll
  for (int i = 0; i < 8; i++) e[i] = 0.f;
  {
    short8 qa = *(const short8*)&qrow[quad * 16];
    short8 qc = *(const short8*)&qrow[quad * 16 + 8];
#pragma unroll
    for (int jj = 0; jj < 8; jj++) {
      float qla = bf2f((u16)qa[jj]) * 256.0f;  // qs holds q*0.125; ql = q_scaled*256
      float qlb = bf2f((u16)qc[jj]) * 256.0f;
      int j = quad * 16 + jj;
#pragma unroll
      for (int i = 0; i < 8; i++) {
        e[i] += qla * gw[i * 64 + j];
        e[i] += qlb * gw[i * 64 + j + 8];
      }
    }
  }
#pragma unroll
  for (int i = 0; i < 8; i++) {
    e[i] += __shfl_xor(e[i], 16, 64);
    e[i] += __shfl_xor(e[i], 32, 64);
  }
  float u0 = e[0] + e[1] + e[2] + e[3] + gb[0] + gb[1] + gb[2] + gb[3];
  float u1 = e[4] + e[5] + e[6] + e[7] + gb[4] + gb[5] + gb[6] + gb[7];
  float sa = 1.0f / (1.0f + __expf(-u0));
  float sc_ = 1.0f / (1.0f + __expf(-u1));
  float gv = sa * (sc_ * ga[h] - 1.0f) + 2.0f;  // lane-local: l15 == q-row

  short8 qf0 = *(const short8*)&Q[(q0 + l15) * 64 + quad * 8];
  short8 qf1 = *(const short8*)&Q[(q0 + l15) * 64 + quad * 8 + 32];

  // bias table base: rel = (s0 + quad*4 + r) - (q0 + l15); tb[s0+r], tb[s0+16+r]
  const float* tb = tbl + h * 2048 + 1023 + quad * 4 - (q0 + l15);

  float mrun = -1e30f, lrun = 0.f;
  floatx4 zero4 = {0.f, 0.f, 0.f, 0.f};
  floatx4 accO[4];
#pragma unroll
  for (int ni = 0; ni < 4; ni++) accO[ni] = zero4;

  // prologue: K fragments + bias for step 0
  const u16* Kr = K + l15 * 64 + quad * 8;
  short8 ka0 = *(const short8*)&Kr[0];
  short8 ka1 = *(const short8*)&Kr[32];
  short8 kb0 = *(const short8*)&Kr[16 * 64];
  short8 kb1 = *(const short8*)&Kr[16 * 64 + 32];
  float bt[8];
#pragma unroll
  for (int r = 0; r < 4; r++) { bt[r] = tb[r]; bt[4 + r] = tb[16 + r]; }

  for (int it = 0; it < 32; it++) {
    int s0 = it * 32;
    // ---- QK^T swapped: A=K (rows=s), B=Q (cols=q) -> C[s][q], q = l15 lane-local ----
    floatx4 sc0 = zero4, sc1 = zero4;
    sc0 = MFMA16(ka0, qf0, sc0);
    sc0 = MFMA16(ka1, qf1, sc0);
    sc1 = MFMA16(kb0, qf0, sc1);
    sc1 = MFMA16(kb1, qf1, sc1);

    // ---- prefetch next K + bias; load current V (lands under softmax VALU) ----
    int sn = (s0 + 32) & 1023;
    const u16* Kn = K + (sn + l15) * 64 + quad * 8;
    short8 na0 = *(const short8*)&Kn[0];
    short8 na1 = *(const short8*)&Kn[32];
    short8 nb0 = *(const short8*)&Kn[16 * 64];
    short8 nb1 = *(const short8*)&Kn[16 * 64 + 32];
    float btn[8];
#pragma unroll
    for (int r = 0; r < 4; r++) { btn[r] = tb[sn + r]; btn[4 + r] = tb[sn + 16 + r]; }
    short8 vf0 = *(const short8*)&V[(0 * 16 + l15) * 1024 + s0 + quad * 8];
    short8 vf1 = *(const short8*)&V[(1 * 16 + l15) * 1024 + s0 + quad * 8];
    short8 vf2 = *(const short8*)&V[(2 * 16 + l15) * 1024 + s0 + quad * 8];
    short8 vf3 = *(const short8*)&V[(3 * 16 + l15) * 1024 + s0 + quad * 8];

    // ---- softmax: per lane 8 scores for q=l15, s = quad*4+r (+16); reduce over quad bits ----
    float vv[8];
#pragma unroll
    for (int r = 0; r < 4; r++) {
      vv[r]     = sc0[r] + gv * bt[r];
      vv[4 + r] = sc1[r] + gv * bt[4 + r];
    }
    float mt = fmaxf(fmaxf(fmaxf(vv[0], vv[1]), fmaxf(vv[2], vv[3])),
                     fmaxf(fmaxf(vv[4], vv[5]), fmaxf(vv[6], vv[7])));
    mt = fmaxf(mt, __shfl_xor(mt, 16, 64));
    mt = fmaxf(mt, __shfl_xor(mt, 32, 64));
    float mnew = fmaxf(mrun, mt);
    float al = __expf(fmaxf(mrun - mnew, -80.0f));  // first-iter safe
    float p[8], ps = 0.f;
#pragma unroll
    for (int j = 0; j < 8; j++) { p[j] = __expf(vv[j] - mnew); ps += p[j]; }
    ps += __shfl_xor(ps, 16, 64);
    ps += __shfl_xor(ps, 32, 64);
    lrun = lrun * al + ps;
    mrun = mnew;

    // rescale accO rows (row q = quad*4+r; alpha lives at lane l15==q)
    float ar[4];
#pragma unroll
    for (int r = 0; r < 4; r++) ar[r] = __shfl(al, quad * 4 + r, 64);
#pragma unroll
    for (int ni = 0; ni < 4; ni++) {
      floatx4 t = accO[ni];
      t[0] *= ar[0]; t[1] *= ar[1]; t[2] *= ar[2]; t[3] *= ar[3];
      accO[ni] = t;
    }

    // ---- pack P -> bf16 and bounce through per-wave LDS into A-fragment layout ----
    unsigned w0, w1, w2, w3;
    asm("v_cvt_pk_bf16_f32 %0, %1, %2" : "=v"(w0) : "v"(p[0]), "v"(p[1]));
    asm("v_cvt_pk_bf16_f32 %0, %1, %2" : "=v"(w1) : "v"(p[2]), "v"(p[3]));
    asm("v_cvt_pk_bf16_f32 %0, %1, %2" : "=v"(w2) : "v"(p[4]), "v"(p[5]));
    asm("v_cvt_pk_bf16_f32 %0, %1, %2" : "=v"(w3) : "v"(p[6]), "v"(p[7]));
    u16* pw = pbase + (it & 1) * 768;
    uint2 wa; wa.x = w0; wa.y = w1;
    uint2 wbv; wbv.x = w2; wbv.y = w3;
    *(uint2*)&pw[l15 * 48 + quad * 4] = wa;            // s = quad*4 + 0..3
    *(uint2*)&pw[l15 * 48 + 16 + quad * 4] = wbv;      // s = 16 + quad*4 + 0..3
    asm volatile("s_waitcnt lgkmcnt(0)" ::: "memory"); // wave-private: no block barrier needed
    __builtin_amdgcn_sched_barrier(0);
    short8 pf = *(const short8*)&pw[l15 * 48 + quad * 8];

    // ---- PV (unchanged layout): C[q][hd] ----
    accO[0] = MFMA16(pf, vf0, accO[0]);
    accO[1] = MFMA16(pf, vf1, accO[1]);
    accO[2] = MFMA16(pf, vf2, accO[2]);
    accO[3] = MFMA16(pf, vf3, accO[3]);

    ka0 = na0; ka1 = na1; kb0 = nb0; kb1 = nb1;
#pragma unroll
    for (int j = 0; j < 8; j++) bt[j] = btn[j];
  }

#pragma unroll
  for (int r = 0; r < 4; r++) {
    float lr = __shfl(lrun, quad * 4 + r, 64);
    float rl = 1.0f / lr;
    int t = q0 + quad * 4 + r;
#pragma unroll
    for (int ni = 0; ni < 4; ni++) {
      ao[(b * 1024 + t) * 1024 + h * 64 + ni * 16 + l15] = f2bf(accO[ni][r] * rl);
    }
  }
}

// ---------------------------------------------------------------- output projection + residual (fp32 out)
__global__ __launch_bounds__(256) void oproj_kernel(
    const u16* __restrict__ ao, const u16* __restrict__ wob, const float* __restrict__ bo,
    const float* __restrict__ x, float* __restrict__ out)
{
  __shared__ u16 As[128 * 32];
  __shared__ u16 Bs[128 * 32];
  int tid = threadIdx.x;
  int wid = tid >> 6, lane = tid & 63;
  int wm = wid >> 1, wn = wid & 1;
  int l15 = lane & 15, quad = lane >> 4;
  int m0 = blockIdx.y * 128;
  int n0 = blockIdx.x * 128;

  floatx4 zero4 = {0.f, 0.f, 0.f, 0.f};
  floatx4 acc[4][4];
#pragma unroll
  for (int i = 0; i < 4; i++)
#pragma unroll
    for (int j = 0; j < 4; j++) acc[i][j] = zero4;

  int lr = tid >> 2;
  int lc = (tid & 3) * 8;

  for (int kt = 0; kt < 1024; kt += 32) {
    *(short8*)&As[lr * 32 + lc]        = *(const short8*)&ao[(m0 + lr) * 1024 + kt + lc];
    *(short8*)&As[(lr + 64) * 32 + lc] = *(const short8*)&ao[(m0 + lr + 64) * 1024 + kt + lc];
    *(short8*)&Bs[lr * 32 + lc]        = *(const short8*)&wob[(n0 + lr) * 1024 + kt + lc];
    *(short8*)&Bs[(lr + 64) * 32 + lc] = *(const short8*)&wob[(n0 + lr + 64) * 1024 + kt + lc];
    __syncthreads();
    short8 af[4], bf[4];
#pragma unroll
    for (int mi = 0; mi < 4; mi++)
      af[mi] = *(const short8*)&As[(wm * 64 + mi * 16 + l15) * 32 + quad * 8];
#pragma unroll
    for (int ni = 0; ni < 4; ni++)
      bf[ni] = *(const short8*)&Bs[(wn * 64 + ni * 16 + l15) * 32 + quad * 8];
#pragma unroll
    for (int mi = 0; mi < 4; mi++)
#pragma unroll
      for (int ni = 0; ni < 4; ni++)
        acc[mi][ni] = MFMA16(af[mi], bf[ni], acc[mi][ni]);
    __syncthreads();
  }

#pragma unroll
  for (int mi = 0; mi < 4; mi++) {
#pragma unroll
    for (int ni = 0; ni < 4; ni++) {
#pragma unroll
      for (int r = 0; r < 4; r++) {
        int row = m0 + wm * 64 + mi * 16 + quad * 4 + r;
        int c = n0 + wn * 64 + ni * 16 + l15;
        out[row * 1024 + c] = acc[mi][ni][r] + bo[c] + x[row * 1024 + c];
      }
    }
  }
}

// ---------------------------------------------------------------- pos_bias_out: compute + write ALL 4 batch copies
__global__ __launch_bounds__(256) void bias_all_kernel(
    const float* __restrict__ rel_emb, float* __restrict__ out1)
{
  int tid = blockIdx.x * 256 + threadIdx.x;  // 131072 total
  int t = tid >> 7;
  int s0 = (tid & 127) * 8;
  int bkt[8];
#pragma unroll
  for (int j = 0; j < 8; j++) bkt[j] = rel_bucket(t, s0 + j) * 16;
  int base_ts = t * 1024 + s0;
#pragma unroll
  for (int hh = 0; hh < 16; hh++) {
    float4 v0, v1;
    v0.x = rel_emb[bkt[0] + hh]; v0.y = rel_emb[bkt[1] + hh];
    v0.z = rel_emb[bkt[2] + hh]; v0.w = rel_emb[bkt[3] + hh];
    v1.x = rel_emb[bkt[4] + hh]; v1.y = rel_emb[bkt[5] + hh];
    v1.z = rel_emb[bkt[6] + hh]; v1.w = rel_emb[bkt[7] + hh];
    float* p = out1 + hh * 1048576 + base_ts;
    *(float4*)p = v0;              *(float4*)(p + 4) = v1;
    *(float4*)(p + 16777216) = v0; *(float4*)(p + 16777216 + 4) = v1;
    *(float4*)(p + 33554432) = v0; *(float4*)(p + 33554432 + 4) = v1;
    *(float4*)(p + 50331648) = v0; *(float4*)(p + 50331648 + 4) = v1;
  }
}

// ---------------------------------------------------------------- launch
extern "C" void kernel_launch(void* const* d_in, const int* in_sizes, int n_in,
                              void* d_out, int out_size, void* d_ws, size_t ws_size,
                              hipStream_t stream) {
  const float* x    = (const float*)d_in[0];
  const float* ln_w = (const float*)d_in[1];
  const float* ln_b = (const float*)d_in[2];
  const float* wq   = (const float*)d_in[3];
  const float* bq   = (const float*)d_in[4];
  const float* wk   = (const float*)d_in[5];
  const float* bk   = (const float*)d_in[6];
  const float* wv   = (const float*)d_in[7];
  const float* bv   = (const float*)d_in[8];
  const float* wo   = (const float*)d_in[9];
  const float* bo   = (const float*)d_in[10];
  const float* rel  = (const float*)d_in[11];
  const float* gw   = (const float*)d_in[12];
  const float* gb   = (const float*)d_in[13];
  const float* ga   = (const float*)d_in[14];

  float* out0  = (float*)d_out;
  float* out1f = out0 + 4194304;   // pos_bias_out region, 64M floats (256 MB)

  // ---- bf16 scratch lives INSIDE out1's b=1 region ([16M,32M) floats = 64 MB).
  // bias_all overwrites b=0..3 LAST, after all consumers (attn reads only tbl now).
  u16* hbb  = (u16*)(out1f + 16777216);   // 8 MB  LN(x) bf16
  u16* wbb  = (u16*)(out1f + 18874368);   // 8 MB  wq|wk|wv|wo bf16
  u16* qsb  = (u16*)(out1f + 20971520);   // 8 MB  q*0.125 [b,h,t,hd]
  u16* kkb  = (u16*)(out1f + 23068672);   // 8 MB  k [b,h,t,hd]
  u16* vnb  = (u16*)(out1f + 25165824);   // 8 MB  v [b,h,t,hd]
  u16* vtb  = (u16*)(out1f + 27262976);   // 8 MB  v [b,h,hd,t]
  u16* aob  = (u16*)(out1f + 29360128);   // 8 MB  attn out [b*t, d]
  float* tbl =        out1f + 31457280;   // 128 KB bias table [h][2048]

  ln_kernel<<<1024, 256, 0, stream>>>(x, ln_w, ln_b, hbb);
  convw_kernel<<<2048, 256, 0, stream>>>(wq, wk, wv, wo, wbb);
  bias_table_kernel<<<128, 256, 0, stream>>>(rel, tbl);
  qkv_kernel<<<dim3(24, 32), 256, 0, stream>>>(hbb, wbb, bq, bk, bv, qsb, kkb, vnb);
  vtrans_kernel<<<1024, 256, 0, stream>>>(vnb, vtb);
  attn_kernel<<<dim3(64, 16), 256, 0, stream>>>(qsb, kkb, vtb, gw, gb, ga, tbl, aob);
  oproj_kernel<<<dim3(8, 32), 256, 0, stream>>>(aob, wbb + 3145728, bo, x, out0);
  bias_all_kernel<<<512, 256, 0, stream>>>(rel, out1f);   // writes all 4 batch copies
}

// Round 2
// 524.562 us; speedup vs baseline: 1.0249x; 1.0168x over previous
//
#include <hip/hip_runtime.h>

typedef unsigned short u16;
typedef __attribute__((ext_vector_type(8))) short short8;
typedef __attribute__((ext_vector_type(4))) float floatx4;

#define MFMA16(a, b, c) __builtin_amdgcn_mfma_f32_16x16x32_bf16(a, b, c, 0, 0, 0)

// direct global->LDS async copy, 16B per lane (m97 pattern: LDS dest is lane-linear)
#define GLL16(gp, lp)                                                              \
  __builtin_amdgcn_global_load_lds(                                                \
      (const __attribute__((address_space(1))) void*)(gp),                         \
      (__attribute__((address_space(3))) void*)(lp), 16, 0, 0)

__device__ __forceinline__ float bf2f(u16 u) {
  return __uint_as_float(((unsigned int)u) << 16);
}
__device__ __forceinline__ u16 f2bf(float f) {
  unsigned int u = __float_as_uint(f);
  unsigned int r = (u + 0x7fffu + ((u >> 16) & 1u)) >> 16;
  return (u16)r;
}

// ---------------------------------------------------------------- LayerNorm: fp32 x -> bf16 h
__global__ __launch_bounds__(256) void ln_kernel(
    const float* __restrict__ x, const float* __restrict__ w, const float* __restrict__ bb,
    u16* __restrict__ hb)
{
  int wid = threadIdx.x >> 6, lane = threadIdx.x & 63;
  int row = blockIdx.x * 4 + wid;
  const float* xr = x + row * 1024 + lane * 16;
  float xs[16];
#pragma unroll
  for (int i = 0; i < 4; i++) {
    float4 v = *(const float4*)(xr + i * 4);
    xs[i * 4 + 0] = v.x; xs[i * 4 + 1] = v.y; xs[i * 4 + 2] = v.z; xs[i * 4 + 3] = v.w;
  }
  float s = 0.f, ss = 0.f;
#pragma unroll
  for (int i = 0; i < 16; i++) { s += xs[i]; ss += xs[i] * xs[i]; }
#pragma unroll
  for (int m = 1; m < 64; m <<= 1) { s += __shfl_xor(s, m, 64); ss += __shfl_xor(ss, m, 64); }
  float mu = s * (1.0f / 1024.0f);
  float var = ss * (1.0f / 1024.0f) - mu * mu;
  float rstd = rsqrtf(var + 1e-5f);
  const float* wr = w + lane * 16;
  const float* br = bb + lane * 16;
  short8 o0, o1;
#pragma unroll
  for (int i = 0; i < 8; i++) {
    o0[i] = (short)f2bf((xs[i] - mu) * rstd * wr[i] + br[i]);
    o1[i] = (short)f2bf((xs[8 + i] - mu) * rstd * wr[8 + i] + br[8 + i]);
  }
  u16* hr = hb + row * 1024 + lane * 16;
  *(short8*)hr = o0;
  *(short8*)(hr + 8) = o1;
}

// ---------------------------------------------------------------- relative bucket helper
__device__ __forceinline__ int rel_bucket(int t, int s) {
  int rel = s - t;
  int bucket = (rel > 0) ? 160 : 0;
  int n = (rel < 0) ? -rel : rel;
  if (n < 80) return bucket + n;
  float a = logf((float)n / 80.0f);          // f32, mirrors np order of ops
  float c = a / (float)2.302585092994046;    // np.log(10.0)
  float v = c * 80.0f;
  int large = 80 + (int)v;                   // trunc toward zero (v >= 0)
  if (large > 159) large = 159;
  return bucket + large;
}

// ---------------------------------------------------------------- convert wq|wk|wv|wo fp32 -> bf16  (+ bias table tail blocks)
__global__ __launch_bounds__(256) void convw_kernel(
    const float* __restrict__ wq, const float* __restrict__ wk,
    const float* __restrict__ wv, const float* __restrict__ wo,
    u16* __restrict__ wb, const float* __restrict__ rel_emb, float* __restrict__ tbl)
{
  int bid = blockIdx.x;
  if (bid >= 2048) {
    // bias table: tbl[h][2048], rel = ri-1023
    int idx = (bid - 2048) * 256 + threadIdx.x;  // [0, 32768)
    int h = idx & 15, ri = idx >> 4;             // ri in [0,2048)
    float v = 0.f;
    if (ri < 2047) {
      int rel = ri - 1023;
      v = rel_emb[rel_bucket(0, rel) * 16 + h];
    }
    tbl[h * 2048 + ri] = v;
    return;
  }
  int idx = (bid * 256 + threadIdx.x) * 8;  // [0, 4M)
  int seg = idx >> 20, off = idx & 1048575;
  const float* s = (seg == 0) ? wq : (seg == 1) ? wk : (seg == 2) ? wv : wo;
  float4 f0 = *(const float4*)(s + off);
  float4 f1 = *(const float4*)(s + off + 4);
  short8 o;
  o[0] = (short)f2bf(f0.x); o[1] = (short)f2bf(f0.y);
  o[2] = (short)f2bf(f0.z); o[3] = (short)f2bf(f0.w);
  o[4] = (short)f2bf(f1.x); o[5] = (short)f2bf(f1.y);
  o[6] = (short)f2bf(f1.z); o[7] = (short)f2bf(f1.w);
  *(short8*)&wb[idx] = o;
}

// ---------------------------------------------------------------- fused QKV GEMM (bf16 operands)
// q scaled by 0.125 -> [b,h,t,hd]; k -> [b,h,t,hd]; v -> [b,h,t,hd] (transposed later). All bf16.
__global__ __launch_bounds__(256) void qkv_kernel(
    const u16* __restrict__ hb, const u16* __restrict__ wb,
    const float* __restrict__ bq, const float* __restrict__ bk, const float* __restrict__ bv,
    u16* __restrict__ qs, u16* __restrict__ kko, u16* __restrict__ vn)
{
  __shared__ __align__(16) u16 As[128 * 32];
  __shared__ __align__(16) u16 Bs[128 * 32];
  int tid = threadIdx.x;
  int wid = tid >> 6, lane = tid & 63;
  int wm = wid >> 1, wn = wid & 1;
  int l15 = lane & 15, quad = lane >> 4;
  int m0 = blockIdx.y * 128;
  int n0g = blockIdx.x * 128;
  int sec = n0g >> 10;
  int n0 = n0g & 1023;
  const u16* W = wb + sec * 1048576;
  const float* bias = (sec == 0) ? bq : ((sec == 1) ? bk : bv);

  floatx4 zero4 = {0.f, 0.f, 0.f, 0.f};
  floatx4 acc[4][4];
#pragma unroll
  for (int i = 0; i < 4; i++)
#pragma unroll
    for (int j = 0; j < 4; j++) acc[i][j] = zero4;

  int lr = tid >> 2;
  int lc = (tid & 3) * 8;
  const u16* ga0 = &hb[(m0 + lr) * 1024 + lc];
  const u16* ga1 = &hb[(m0 + lr + 64) * 1024 + lc];
  const u16* gb0 = &W[(n0 + lr) * 1024 + lc];
  const u16* gb1 = &W[(n0 + lr + 64) * 1024 + lc];
  u16* la0 = &As[lr * 32 + lc];
  u16* la1 = &As[(lr + 64) * 32 + lc];
  u16* lb0 = &Bs[lr * 32 + lc];
  u16* lb1 = &Bs[(lr + 64) * 32 + lc];

  for (int kt = 0; kt < 1024; kt += 32) {
    GLL16(ga0 + kt, la0);
    GLL16(ga1 + kt, la1);
    GLL16(gb0 + kt, lb0);
    GLL16(gb1 + kt, lb1);
    __syncthreads();
    short8 af[4], bf[4];
#pragma unroll
    for (int mi = 0; mi < 4; mi++)
      af[mi] = *(const short8*)&As[(wm * 64 + mi * 16 + l15) * 32 + quad * 8];
#pragma unroll
    for (int ni = 0; ni < 4; ni++)
      bf[ni] = *(const short8*)&Bs[(wn * 64 + ni * 16 + l15) * 32 + quad * 8];
#pragma unroll
    for (int mi = 0; mi < 4; mi++)
#pragma unroll
      for (int ni = 0; ni < 4; ni++)
        acc[mi][ni] = MFMA16(af[mi], bf[ni], acc[mi][ni]);
    __syncthreads();
  }

  int bidx = m0 >> 10;  // batch (128 divides 1024, so uniform per block)
#pragma unroll
  for (int mi = 0; mi < 4; mi++) {
#pragma unroll
    for (int ni = 0; ni < 4; ni++) {
#pragma unroll
      for (int r = 0; r < 4; r++) {
        int row = m0 + wm * 64 + mi * 16 + quad * 4 + r;
        int t = row & 1023;
        int c = n0 + wn * 64 + ni * 16 + l15;   // 0..1023 within section
        float val = acc[mi][ni][r] + bias[c];
        int hh = c >> 6, hp = c & 63;
        if (sec == 0) {
          val *= 0.125f;
          qs[((bidx * 16 + hh) * 1024 + t) * 64 + hp] = f2bf(val);
        } else if (sec == 1) {
          kko[((bidx * 16 + hh) * 1024 + t) * 64 + hp] = f2bf(val);
        } else {
          vn[((bidx * 16 + hh) * 1024 + t) * 64 + hp] = f2bf(val);  // coalesced; transpose in vtrans
        }
      }
    }
  }
}

// ---------------------------------------------------------------- V transpose: [bh][t][hd] -> [bh][hd][t]
__global__ __launch_bounds__(256) void vtrans_kernel(
    const u16* __restrict__ vn, u16* __restrict__ vt)
{
  __shared__ u16 Ts[64 * 72];
  int bh = blockIdx.x >> 4;
  int t0 = (blockIdx.x & 15) * 64;
  int tid = threadIdx.x;
  int row = tid >> 2;            // 0..63
  int c16 = (tid & 3) * 16;      // 0,16,32,48
  const u16* src = vn + bh * 65536 + (t0 + row) * 64 + c16;
  *(short8*)&Ts[row * 72 + c16]     = *(const short8*)&src[0];
  *(short8*)&Ts[row * 72 + c16 + 8] = *(const short8*)&src[8];
  __syncthreads();
  short8 o0, o1;
#pragma unroll
  for (int j = 0; j < 8; j++) {
    o0[j] = (short)Ts[(c16 + j) * 72 + row];
    o1[j] = (short)Ts[(c16 + 8 + j) * 72 + row];
  }
  u16* dst = vt + bh * 65536 + row * 1024 + t0 + c16;
  *(short8*)&dst[0] = o0;
  *(short8*)&dst[8] = o1;
}

// ---------------------------------------------------------------- flash attention (gate fused, swapped-QK softmax)
// grid (64 bh, 16 qtiles); 4 waves/block, each wave owns 16 q-rows (q = l15-local), s-steps of 32.
__global__ __launch_bounds__(256) void attn_kernel(
    const u16* __restrict__ qs, const u16* __restrict__ kko, const u16* __restrict__ vt,
    const float* __restrict__ gw, const float* __restrict__ gb, const float* __restrict__ ga,
    const float* __restrict__ tbl, u16* __restrict__ ao)
{
  __shared__ __align__(16) u16 Pb[4][2 * 768];  // per-wave double-buffered: 16 rows x 48 stride
  int wid = threadIdx.x >> 6, lane = threadIdx.x & 63;
  int l15 = lane & 15, quad = lane >> 4;
  int bh = blockIdx.x;
  int b = bh >> 4, h = bh & 15;
  int q0 = blockIdx.y * 64 + wid * 16;
  const u16* Q = qs + bh * 65536;
  const u16* K = kko + bh * 65536;
  const u16* V = vt + bh * 65536;       // [hd][t]
  u16* pbase = &Pb[wid][0];

  // ---- gate for q-row q0 + l15; quads split the 64-dim dot, xor-reduce ----
  const u16* qrow = Q + (q0 + l15) * 64;
  float e[8];
#pragma unroll
  for (int i = 0; i < 8; i++) e[i] = 0.f;
  {
    short8 qa = *(const short8*)&qrow[quad * 16];
    short8 qc = *(const short8*)&qrow[quad * 16 + 8];
#pragma unroll
    for (int jj = 0; jj < 8; jj++) {
      float qla = bf2f((u16)qa[jj]) * 256.0f;  // qs holds q*0.125; ql = q_scaled*256
      float qlb = bf2f((u16)qc[jj]) * 256.0f;
      int j = quad * 16 + jj;
#pragma unroll
      for (int i = 0; i < 8; i++) {
        e[i] += qla * gw[i * 64 + j];
        e[i] += qlb * gw[i * 64 + j + 8];
      }
    }
  }
#pragma unroll
  for (int i = 0; i < 8; i++) {
    e[i] += __shfl_xor(e[i], 16, 64);
    e[i] += __shfl_xor(e[i], 32, 64);
  }
  float u0 = e[0] + e[1] + e[2] + e[3] + gb[0] + gb[1] + gb[2] + gb[3];
  float u1 = e[4] + e[5] + e[6] + e[7] + gb[4] + gb[5] + gb[6] + gb[7];
  float sa = 1.0f / (1.0f + __expf(-u0));
  float sc_ = 1.0f / (1.0f + __expf(-u1));
  float gv = sa * (sc_ * ga[h] - 1.0f) + 2.0f;  // lane-local: l15 == q-row

  short8 qf0 = *(const short8*)&Q[(q0 + l15) * 64 + quad * 8];
  short8 qf1 = *(const short8*)&Q[(q0 + l15) * 64 + quad * 8 + 32];

  // bias table base: rel = (s0 + quad*4 + r) - (q0 + l15); tb[s0+r], tb[s0+16+r]
  const float* tb = tbl + h * 2048 + 1023 + quad * 4 - (q0 + l15);

  float mrun = -1e30f, lrun = 0.f;
  floatx4 zero4 = {0.f, 0.f, 0.f, 0.f};
  floatx4 accO[4];
#pragma unroll
  for (int ni = 0; ni < 4; ni++) accO[ni] = zero4;

  // prologue: K fragments + bias for step 0
  const u16* Kr = K + l15 * 64 + quad * 8;
  short8 ka0 = *(const short8*)&Kr[0];
  short8 ka1 = *(const short8*)&Kr[32];
  short8 kb0 = *(const short8*)&Kr[16 * 64];
  short8 kb1 = *(const short8*)&Kr[16 * 64 + 32];
  float bt[8];
#pragma unroll
  for (int r = 0; r < 4; r++) { bt[r] = tb[r]; bt[4 + r] = tb[16 + r]; }

  for (int it = 0; it < 32; it++) {
    int s0 = it * 32;
    // ---- QK^T swapped: A=K (rows=s), B=Q (cols=q) -> C[s][q], q = l15 lane-local ----
    floatx4 sc0 = zero4, sc1 = zero4;
    sc0 = MFMA16(ka0, qf0, sc0);
    sc0 = MFMA16(ka1, qf1, sc0);
    sc1 = MFMA16(kb0, qf0, sc1);
    sc1 = MFMA16(kb1, qf1, sc1);

    // ---- prefetch next K + bias; load current V (lands under softmax VALU) ----
    int sn = (s0 + 32) & 1023;
    const u16* Kn = K + (sn + l15) * 64 + quad * 8;
    short8 na0 = *(const short8*)&Kn[0];
    short8 na1 = *(const short8*)&Kn[32];
    short8 nb0 = *(const short8*)&Kn[16 * 64];
    short8 nb1 = *(const short8*)&Kn[16 * 64 + 32];
    float btn[8];
#pragma unroll
    for (int r = 0; r < 4; r++) { btn[r] = tb[sn + r]; btn[4 + r] = tb[sn + 16 + r]; }
    short8 vf0 = *(const short8*)&V[(0 * 16 + l15) * 1024 + s0 + quad * 8];
    short8 vf1 = *(const short8*)&V[(1 * 16 + l15) * 1024 + s0 + quad * 8];
    short8 vf2 = *(const short8*)&V[(2 * 16 + l15) * 1024 + s0 + quad * 8];
    short8 vf3 = *(const short8*)&V[(3 * 16 + l15) * 1024 + s0 + quad * 8];

    // ---- softmax: per lane 8 scores for q=l15, s = quad*4+r (+16); reduce over quad bits ----
    float vv[8];
#pragma unroll
    for (int r = 0; r < 4; r++) {
      vv[r]     = sc0[r] + gv * bt[r];
      vv[4 + r] = sc1[r] + gv * bt[4 + r];
    }
    float mt = fmaxf(fmaxf(fmaxf(vv[0], vv[1]), fmaxf(vv[2], vv[3])),
                     fmaxf(fmaxf(vv[4], vv[5]), fmaxf(vv[6], vv[7])));
    mt = fmaxf(mt, __shfl_xor(mt, 16, 64));
    mt = fmaxf(mt, __shfl_xor(mt, 32, 64));
    float mnew = fmaxf(mrun, mt);
    float al = __expf(fmaxf(mrun - mnew, -80.0f));  // first-iter safe
    float p[8], ps = 0.f;
#pragma unroll
    for (int j = 0; j < 8; j++) { p[j] = __expf(vv[j] - mnew); ps += p[j]; }
    ps += __shfl_xor(ps, 16, 64);
    ps += __shfl_xor(ps, 32, 64);
    lrun = lrun * al + ps;
    mrun = mnew;

    // rescale accO rows (row q = quad*4+r; alpha lives at lane l15==q)
    float ar[4];
#pragma unroll
    for (int r = 0; r < 4; r++) ar[r] = __shfl(al, quad * 4 + r, 64);
#pragma unroll
    for (int ni = 0; ni < 4; ni++) {
      floatx4 t = accO[ni];
      t[0] *= ar[0]; t[1] *= ar[1]; t[2] *= ar[2]; t[3] *= ar[3];
      accO[ni] = t;
    }

    // ---- pack P -> bf16 and bounce through per-wave LDS into A-fragment layout ----
    unsigned w0, w1, w2, w3;
    asm("v_cvt_pk_bf16_f32 %0, %1, %2" : "=v"(w0) : "v"(p[0]), "v"(p[1]));
    asm("v_cvt_pk_bf16_f32 %0, %1, %2" : "=v"(w1) : "v"(p[2]), "v"(p[3]));
    asm("v_cvt_pk_bf16_f32 %0, %1, %2" : "=v"(w2) : "v"(p[4]), "v"(p[5]));
    asm("v_cvt_pk_bf16_f32 %0, %1, %2" : "=v"(w3) : "v"(p[6]), "v"(p[7]));
    u16* pw = pbase + (it & 1) * 768;
    uint2 wa; wa.x = w0; wa.y = w1;
    uint2 wbv; wbv.x = w2; wbv.y = w3;
    *(uint2*)&pw[l15 * 48 + quad * 4] = wa;            // s = quad*4 + 0..3
    *(uint2*)&pw[l15 * 48 + 16 + quad * 4] = wbv;      // s = 16 + quad*4 + 0..3
    asm volatile("s_waitcnt lgkmcnt(0)" ::: "memory"); // wave-private: no block barrier needed
    __builtin_amdgcn_sched_barrier(0);
    short8 pf = *(const short8*)&pw[l15 * 48 + quad * 8];

    // ---- PV (unchanged layout): C[q][hd] ----
    accO[0] = MFMA16(pf, vf0, accO[0]);
    accO[1] = MFMA16(pf, vf1, accO[1]);
    accO[2] = MFMA16(pf, vf2, accO[2]);
    accO[3] = MFMA16(pf, vf3, accO[3]);

    ka0 = na0; ka1 = na1; kb0 = nb0; kb1 = nb1;
#pragma unroll
    for (int j = 0; j < 8; j++) bt[j] = btn[j];
  }

#pragma unroll
  for (int r = 0; r < 4; r++) {
    float lr = __shfl(lrun, quad * 4 + r, 64);
    float rl = 1.0f / lr;
    int t = q0 + quad * 4 + r;
#pragma unroll
    for (int ni = 0; ni < 4; ni++) {
      ao[(b * 1024 + t) * 1024 + h * 64 + ni * 16 + l15] = f2bf(accO[ni][r] * rl);
    }
  }
}

// ---------------------------------------------------------------- output projection + residual (fp32 out)
__global__ __launch_bounds__(256) void oproj_kernel(
    const u16* __restrict__ ao, const u16* __restrict__ wob, const float* __restrict__ bo,
    const float* __restrict__ x, float* __restrict__ out)
{
  __shared__ __align__(16) u16 As[128 * 32];
  __shared__ __align__(16) u16 Bs[128 * 32];
  int tid = threadIdx.x;
  int wid = tid >> 6, lane = tid & 63;
  int wm = wid >> 1, wn = wid & 1;
  int l15 = lane & 15, quad = lane >> 4;
  int m0 = blockIdx.y * 128;
  int n0 = blockIdx.x * 128;

  floatx4 zero4 = {0.f, 0.f, 0.f, 0.f};
  floatx4 acc[4][4];
#pragma unroll
  for (int i = 0; i < 4; i++)
#pragma unroll
    for (int j = 0; j < 4; j++) acc[i][j] = zero4;

  int lr = tid >> 2;
  int lc = (tid & 3) * 8;
  const u16* ga0 = &ao[(m0 + lr) * 1024 + lc];
  const u16* ga1 = &ao[(m0 + lr + 64) * 1024 + lc];
  const u16* gb0 = &wob[(n0 + lr) * 1024 + lc];
  const u16* gb1 = &wob[(n0 + lr + 64) * 1024 + lc];
  u16* la0 = &As[lr * 32 + lc];
  u16* la1 = &As[(lr + 64) * 32 + lc];
  u16* lb0 = &Bs[lr * 32 + lc];
  u16* lb1 = &Bs[(lr + 64) * 32 + lc];

  for (int kt = 0; kt < 1024; kt += 32) {
    GLL16(ga0 + kt, la0);
    GLL16(ga1 + kt, la1);
    GLL16(gb0 + kt, lb0);
    GLL16(gb1 + kt, lb1);
    __syncthreads();
    short8 af[4], bf[4];
#pragma unroll
    for (int mi = 0; mi < 4; mi++)
      af[mi] = *(const short8*)&As[(wm * 64 + mi * 16 + l15) * 32 + quad * 8];
#pragma unroll
    for (int ni = 0; ni < 4; ni++)
      bf[ni] = *(const short8*)&Bs[(wn * 64 + ni * 16 + l15) * 32 + quad * 8];
#pragma unroll
    for (int mi = 0; mi < 4; mi++)
#pragma unroll
      for (int ni = 0; ni < 4; ni++)
        acc[mi][ni] = MFMA16(af[mi], bf[ni], acc[mi][ni]);
    __syncthreads();
  }

#pragma unroll
  for (int mi = 0; mi < 4; mi++) {
#pragma unroll
    for (int ni = 0; ni < 4; ni++) {
#pragma unroll
      for (int r = 0; r < 4; r++) {
        int row = m0 + wm * 64 + mi * 16 + quad * 4 + r;
        int c = n0 + wn * 64 + ni * 16 + l15;
        out[row * 1024 + c] = acc[mi][ni][r] + bo[c] + x[row * 1024 + c];
      }
    }
  }
}

// ---------------------------------------------------------------- pos_bias_out: compute + write ALL 4 batch copies
__global__ __launch_bounds__(256) void bias_all_kernel(
    const float* __restrict__ rel_emb, float* __restrict__ out1)
{
  int tid = blockIdx.x * 256 + threadIdx.x;  // 131072 total
  int t = tid >> 7;
  int s0 = (tid & 127) * 8;
  int bkt[8];
#pragma unroll
  for (int j = 0; j < 8; j++) bkt[j] = rel_bucket(t, s0 + j) * 16;
  int base_ts = t * 1024 + s0;
#pragma unroll
  for (int hh = 0; hh < 16; hh++) {
    float4 v0, v1;
    v0.x = rel_emb[bkt[0] + hh]; v0.y = rel_emb[bkt[1] + hh];
    v0.z = rel_emb[bkt[2] + hh]; v0.w = rel_emb[bkt[3] + hh];
    v1.x = rel_emb[bkt[4] + hh]; v1.y = rel_emb[bkt[5] + hh];
    v1.z = rel_emb[bkt[6] + hh]; v1.w = rel_emb[bkt[7] + hh];
    float* p = out1 + hh * 1048576 + base_ts;
    *(float4*)p = v0;              *(float4*)(p + 4) = v1;
    *(float4*)(p + 16777216) = v0; *(float4*)(p + 16777216 + 4) = v1;
    *(float4*)(p + 33554432) = v0; *(float4*)(p + 33554432 + 4) = v1;
    *(float4*)(p + 50331648) = v0; *(float4*)(p + 50331648 + 4) = v1;
  }
}

// ---------------------------------------------------------------- launch
extern "C" void kernel_launch(void* const* d_in, const int* in_sizes, int n_in,
                              void* d_out, int out_size, void* d_ws, size_t ws_size,
                              hipStream_t stream) {
  const float* x    = (const float*)d_in[0];
  const float* ln_w = (const float*)d_in[1];
  const float* ln_b = (const float*)d_in[2];
  const float* wq   = (const float*)d_in[3];
  const float* bq   = (const float*)d_in[4];
  const float* wk   = (const float*)d_in[5];
  const float* bk   = (const float*)d_in[6];
  const float* wv   = (const float*)d_in[7];
  const float* bv   = (const float*)d_in[8];
  const float* wo   = (const float*)d_in[9];
  const float* bo   = (const float*)d_in[10];
  const float* rel  = (const float*)d_in[11];
  const float* gw   = (const float*)d_in[12];
  const float* gb   = (const float*)d_in[13];
  const float* ga   = (const float*)d_in[14];

  float* out0  = (float*)d_out;
  float* out1f = out0 + 4194304;   // pos_bias_out region, 64M floats (256 MB)

  // ---- bf16 scratch lives INSIDE out1's b=1 region ([16M,32M) floats = 64 MB).
  // bias_all overwrites b=0..3 LAST, after all consumers (attn reads only tbl now).
  u16* hbb  = (u16*)(out1f + 16777216);   // 8 MB  LN(x) bf16
  u16* wbb  = (u16*)(out1f + 18874368);   // 8 MB  wq|wk|wv|wo bf16
  u16* qsb  = (u16*)(out1f + 20971520);   // 8 MB  q*0.125 [b,h,t,hd]
  u16* kkb  = (u16*)(out1f + 23068672);   // 8 MB  k [b,h,t,hd]
  u16* vnb  = (u16*)(out1f + 25165824);   // 8 MB  v [b,h,t,hd]
  u16* vtb  = (u16*)(out1f + 27262976);   // 8 MB  v [b,h,hd,t]
  u16* aob  = (u16*)(out1f + 29360128);   // 8 MB  attn out [b*t, d]
  float* tbl =        out1f + 31457280;   // 128 KB bias table [h][2048]

  ln_kernel<<<1024, 256, 0, stream>>>(x, ln_w, ln_b, hbb);
  convw_kernel<<<2176, 256, 0, stream>>>(wq, wk, wv, wo, wbb, rel, tbl);
  qkv_kernel<<<dim3(24, 32), 256, 0, stream>>>(hbb, wbb, bq, bk, bv, qsb, kkb, vnb);
  vtrans_kernel<<<1024, 256, 0, stream>>>(vnb, vtb);
  attn_kernel<<<dim3(64, 16), 256, 0, stream>>>(qsb, kkb, vtb, gw, gb, ga, tbl, aob);
  oproj_kernel<<<dim3(8, 32), 256, 0, stream>>>(aob, wbb + 3145728, bo, x, out0);
  bias_all_kernel<<<512, 256, 0, stream>>>(rel, out1f);   // writes all 4 batch copies
}